// Round 4
// baseline (2633.544 us; speedup 1.0000x reference)
//
#include <hip/hip_runtime.h>
#include <hip/hip_bf16.h>

#define KC   1024
#define DD   256
#define NN   32768
#define HWC  1024
#define LOSS_OFF 8388608
#define IDX_OFF  8388609

// Replicate numpy pairwise_sum of a[i]*a[i], n=256 (validated: absmax 0.0 in r2).
__device__ __forceinline__ float np_pairwise_sumsq_256(const float* __restrict__ a) {
#pragma clang fp contract(off)
  float half0, half1;
  {
    const float* p = a;
    float r[8];
#pragma unroll
    for (int j = 0; j < 8; ++j) r[j] = p[j] * p[j];
    for (int i = 8; i < 128; i += 8) {
#pragma unroll
      for (int j = 0; j < 8; ++j) r[j] = r[j] + p[i + j] * p[i + j];
    }
    half0 = ((r[0] + r[1]) + (r[2] + r[3])) + ((r[4] + r[5]) + (r[6] + r[7]));
  }
  {
    const float* p = a + 128;
    float r[8];
#pragma unroll
    for (int j = 0; j < 8; ++j) r[j] = p[j] * p[j];
    for (int i = 8; i < 128; i += 8) {
#pragma unroll
      for (int j = 0; j < 8; ++j) r[j] = r[j] + p[i + j] * p[i + j];
    }
    half1 = ((r[0] + r[1]) + (r[2] + r[3])) + ((r[4] + r[5]) + (r[6] + r[7]));
  }
  return half0 + half1;
}

// K0: e_sq[k] via numpy-pairwise; zero loss accumulator.
__global__ void vq_esq_kernel(const float* __restrict__ cb, float* __restrict__ esq,
                              float* __restrict__ loss_acc) {
  const int k = blockIdx.x * 256 + threadIdx.x;
  if (k == 0) loss_acc[0] = 0.0f;
  if (k < KC) esq[k] = np_pairwise_sumsq_256(cb + ((size_t)k << 8));
}

// K1: fused distance + argmin. 512 threads = 8 waves behind one 64-row x-tile.
// LDS ~70.9 KB -> 2 blocks/CU = 16 waves/CU (~48% occ), vs r2's 8 waves/CU.
// Wave w scans codes [w*128, (w+1)*128); thread row = lane. Ascending wave
// merge preserves lowest-index tie semantics.
__global__ __launch_bounds__(512, 4)
void vq_argmin_kernel(const float* __restrict__ x, const float* __restrict__ cb,
                      const float* __restrict__ esq, int* __restrict__ idxout,
                      float* __restrict__ out) {
  __shared__ float xs[64][260];   // stride 260 floats: 16B-aligned rows for b128
  __shared__ float xsq[64];
  __shared__ float rv[8][64];
  __shared__ int   ri[8][64];

  const int tid  = threadIdx.x;
  const int lane = tid & 63;
  const int w    = __builtin_amdgcn_readfirstlane(tid >> 6);  // wave id -> SGPR
  const int n0   = blockIdx.x << 6;
  const int b    = n0 >> 10;
  const int hw0  = n0 & 1023;
  const float* __restrict__ xb = x + (size_t)b * (DD * HWC) + hw0;

  // Stage x tile: xs[n][d] = x[b, d, hw0+n]; 8 waves x 32 d-columns = all 256.
  // (r3 bug was w<<3 with i<8 -> only 64 columns staged.)
#pragma unroll
  for (int i = 0; i < 32; ++i) {
    const int d = (w << 5) + i;
    xs[lane][d] = xb[(size_t)d * HWC + lane];
  }
  __syncthreads();

  // x_sq per row, numpy-pairwise bitwise (tie reproduction — do not change).
  if (tid < 64) xsq[tid] = np_pairwise_sumsq_256(&xs[tid][0]);
  __syncthreads();

  const float myxsq = xsq[lane];
  float best = 3.4028235e38f;
  int   bidx = 0;
  const int kbase = w << 7;   // 128 codes per wave

  for (int c = 0; c < 32; ++c) {
    const int k = kbase + (c << 2);
    const float* __restrict__ e = cb + ((size_t)k << 8);  // wave-uniform -> s_load
    float a0 = 0.f, a1 = 0.f, a2 = 0.f, a3 = 0.f;
#pragma unroll
    for (int d = 0; d < DD; d += 4) {
      const float4 xv = *(const float4*)&xs[lane][d];
      const float4 e0 = *(const float4*)(e + d);
      const float4 e1 = *(const float4*)(e + 256 + d);
      const float4 e2 = *(const float4*)(e + 512 + d);
      const float4 e3 = *(const float4*)(e + 768 + d);
      a0 = fmaf(xv.x, e0.x, a0); a0 = fmaf(xv.y, e0.y, a0);
      a0 = fmaf(xv.z, e0.z, a0); a0 = fmaf(xv.w, e0.w, a0);
      a1 = fmaf(xv.x, e1.x, a1); a1 = fmaf(xv.y, e1.y, a1);
      a1 = fmaf(xv.z, e1.z, a1); a1 = fmaf(xv.w, e1.w, a1);
      a2 = fmaf(xv.x, e2.x, a2); a2 = fmaf(xv.y, e2.y, a2);
      a2 = fmaf(xv.z, e2.z, a2); a2 = fmaf(xv.w, e2.w, a2);
      a3 = fmaf(xv.x, e3.x, a3); a3 = fmaf(xv.y, e3.y, a3);
      a3 = fmaf(xv.z, e3.z, a3); a3 = fmaf(xv.w, e3.w, a3);
    }
    {
      // Reference rounding: fl(e_sq - fl(2*dot)) then fl(t + x_sq). No FMA here.
#pragma clang fp contract(off)
      const float t0 = esq[k + 0] - 2.0f * a0;
      const float t1 = esq[k + 1] - 2.0f * a1;
      const float t2 = esq[k + 2] - 2.0f * a2;
      const float t3 = esq[k + 3] - 2.0f * a3;
      const float d0 = t0 + myxsq;
      const float d1 = t1 + myxsq;
      const float d2 = t2 + myxsq;
      const float d3 = t3 + myxsq;
      if (d0 < best) { best = d0; bidx = k + 0; }   // strict < : lowest k wins ties
      if (d1 < best) { best = d1; bidx = k + 1; }
      if (d2 < best) { best = d2; bidx = k + 2; }
      if (d3 < best) { best = d3; bidx = k + 3; }
    }
  }

  rv[w][lane] = best;
  ri[w][lane] = bidx;
  __syncthreads();
  if (tid < 64) {
    float bb = rv[0][tid];
    int   bi = ri[0][tid];
#pragma unroll
    for (int ww = 1; ww < 8; ++ww) {
      const float v = rv[ww][tid];
      if (v < bb) { bb = v; bi = ri[ww][tid]; }  // ascending k-order: lowest k on ties
    }
    idxout[n0 + tid] = bi;
    out[IDX_OFF + n0 + tid] = (float)bi;         // fp32 index output
  }
}

// K2: gather codebook rows per block into LDS, write x_q_st (fp32), accumulate loss.
__global__ __launch_bounds__(256, 2)
void vq_gather_kernel(const float* __restrict__ x, const float* __restrict__ cb,
                      const int* __restrict__ idxin, float* __restrict__ loss_acc,
                      float* __restrict__ out) {
  __shared__ float qs[64][260];
  __shared__ int   idx_s[64];
  __shared__ float wr[4];

  const int tid  = threadIdx.x;
  const int lane = tid & 63;
  const int w    = tid >> 6;
  const int n0   = blockIdx.x << 6;
  const int b    = n0 >> 10;
  const int hw0  = n0 & 1023;

  if (tid < 64) idx_s[tid] = idxin[n0 + tid];
  __syncthreads();

  const float4* __restrict__ cb4 = (const float4*)cb;
  for (int r = w; r < 64; r += 4) {
    const int c = idx_s[r];
    const float4 v = cb4[((size_t)c << 6) + lane];  // coalesced 1KB row read per wave
    *(float4*)&qs[r][lane << 2] = v;
  }
  __syncthreads();

  float lsum = 0.f;
  const size_t obase = (size_t)b * (DD * HWC) + hw0 + lane;
  for (int i = 0; i < 64; ++i) {
    const int d = (w << 6) + i;
    const size_t o = obase + (size_t)d * HWC;
    const float q  = qs[lane][d];
    const float xv = x[o];
    {
#pragma clang fp contract(off)
      const float df = q - xv;           // fl(x_q - x)
      out[o] = xv + df;                  // x_q_st = fl(x + fl(x_q - x)), fp32
      lsum = fmaf(df, df, lsum);         // loss accumulation (loose threshold)
    }
  }

  for (int off = 32; off > 0; off >>= 1) lsum += __shfl_down(lsum, off, 64);
  if (lane == 0) wr[w] = lsum;
  __syncthreads();
  if (tid == 0) atomicAdd(loss_acc, (wr[0] + wr[1]) + (wr[2] + wr[3]));
}

// K3: loss = 1.5 * mean((x_q - x)^2), fp32
__global__ void vq_loss_kernel(const float* __restrict__ loss_acc,
                               float* __restrict__ out) {
  if (threadIdx.x == 0) {
    const float m = loss_acc[0] / 8388608.0f;
    out[LOSS_OFF] = m + 0.5f * m;
  }
}

extern "C" void kernel_launch(void* const* d_in, const int* in_sizes, int n_in,
                              void* d_out, int out_size, void* d_ws, size_t ws_size,
                              hipStream_t stream) {
  const float* x  = (const float*)d_in[0];   // [32,256,32,32] fp32
  const float* cb = (const float*)d_in[1];   // [1024,256] fp32
  float* out = (float*)d_out;                // [x_q_st | loss | indices] fp32

  float* esq      = (float*)d_ws;            // 1024 floats
  float* loss_acc = esq + 1024;              // 1 float (zeroed by K0 each call)
  int*   idxbuf   = (int*)(esq + 1040);      // 32768 ints

  hipLaunchKernelGGL(vq_esq_kernel,    dim3(4),   dim3(256), 0, stream, cb, esq, loss_acc);
  hipLaunchKernelGGL(vq_argmin_kernel, dim3(512), dim3(512), 0, stream, x, cb, esq, idxbuf, out);
  hipLaunchKernelGGL(vq_gather_kernel, dim3(512), dim3(256), 0, stream, x, cb, idxbuf, loss_acc, out);
  hipLaunchKernelGGL(vq_loss_kernel,   dim3(1),   dim3(64),  0, stream, loss_acc, out);
}

// Round 5
// 468.065 us; speedup vs baseline: 5.6264x; 5.6264x over previous
//
#include <hip/hip_runtime.h>
#include <hip/hip_bf16.h>

#define KC   1024
#define DD   256
#define NN   32768
#define HWC  1024
#define LOSS_OFF 8388608
#define IDX_OFF  8388609

// Replicate numpy pairwise_sum of a[i]*a[i], n=256 (validated: absmax 0.0 in r2/r4).
__device__ __forceinline__ float np_pairwise_sumsq_256(const float* __restrict__ a) {
#pragma clang fp contract(off)
  float half0, half1;
  {
    const float* p = a;
    float r[8];
#pragma unroll
    for (int j = 0; j < 8; ++j) r[j] = p[j] * p[j];
    for (int i = 8; i < 128; i += 8) {
#pragma unroll
      for (int j = 0; j < 8; ++j) r[j] = r[j] + p[i + j] * p[i + j];
    }
    half0 = ((r[0] + r[1]) + (r[2] + r[3])) + ((r[4] + r[5]) + (r[6] + r[7]));
  }
  {
    const float* p = a + 128;
    float r[8];
#pragma unroll
    for (int j = 0; j < 8; ++j) r[j] = p[j] * p[j];
    for (int i = 8; i < 128; i += 8) {
#pragma unroll
      for (int j = 0; j < 8; ++j) r[j] = r[j] + p[i + j] * p[i + j];
    }
    half1 = ((r[0] + r[1]) + (r[2] + r[3])) + ((r[4] + r[5]) + (r[6] + r[7]));
  }
  return half0 + half1;
}

// K0: e_sq[k] via numpy-pairwise; zero loss accumulator.
__global__ void vq_esq_kernel(const float* __restrict__ cb, float* __restrict__ esq,
                              float* __restrict__ loss_acc) {
  const int k = blockIdx.x * 256 + threadIdx.x;
  if (k == 0) loss_acc[0] = 0.0f;
  if (k < KC) esq[k] = np_pairwise_sumsq_256(cb + ((size_t)k << 8));
}

// K1: fused distance + argmin. 512 threads = 8 waves behind one 64-row x-tile
// (71 KB LDS -> 2 blocks/CU = 16 waves/CU). Wave w scans codes [w*128,(w+1)*128)
// in groups of 8 with a moderately-unrolled d-loop: per d-step 1 ds_read_b128 +
// 8 wave-uniform codebook loads (s_load) + 32 FMAs. Low register pressure by
// construction — r4's __launch_bounds__(512,4) squeezed VGPR to 64 and the
// full-unroll spill traffic (9.4 GB FETCH) was the 3.4x regression.
__global__ __launch_bounds__(512, 2)
void vq_argmin_kernel(const float* __restrict__ x, const float* __restrict__ cb,
                      const float* __restrict__ esq, int* __restrict__ idxout,
                      float* __restrict__ out) {
  __shared__ float xs[64][260];   // stride 260 floats: 16B-aligned rows for b128
  __shared__ float xsq[64];
  __shared__ float rv[8][64];
  __shared__ int   ri[8][64];

  const int tid  = threadIdx.x;
  const int lane = tid & 63;
  const int w    = __builtin_amdgcn_readfirstlane(tid >> 6);  // wave id -> SGPR
  const int n0   = blockIdx.x << 6;
  const int b    = n0 >> 10;
  const int hw0  = n0 & 1023;
  const float* __restrict__ xb = x + (size_t)b * (DD * HWC) + hw0;

  // Stage x tile: xs[n][d] = x[b, d, hw0+n]; 8 waves x 32 d-columns = all 256.
#pragma unroll
  for (int i = 0; i < 32; ++i) {
    const int d = (w << 5) + i;
    xs[lane][d] = xb[(size_t)d * HWC + lane];
  }
  __syncthreads();

  // x_sq per row, numpy-pairwise bitwise (tie reproduction — do not change).
  if (tid < 64) xsq[tid] = np_pairwise_sumsq_256(&xs[tid][0]);
  __syncthreads();

  const float myxsq = xsq[lane];
  float best = 3.4028235e38f;
  int   bidx = 0;
  const int kbase = w << 7;   // 128 codes per wave

  for (int g = 0; g < 16; ++g) {
    const int k = kbase + (g << 3);
    const float* __restrict__ e = cb + ((size_t)k << 8);  // wave-uniform -> s_load
    float acc[8];
#pragma unroll
    for (int j = 0; j < 8; ++j) acc[j] = 0.0f;
#pragma unroll 4
    for (int d = 0; d < DD; d += 4) {
      const float4 xv = *(const float4*)&xs[lane][d];
#pragma unroll
      for (int j = 0; j < 8; ++j) {
        const float4 ev = *(const float4*)(e + (j << 8) + d);
        acc[j] = fmaf(xv.x, ev.x, acc[j]);
        acc[j] = fmaf(xv.y, ev.y, acc[j]);
        acc[j] = fmaf(xv.z, ev.z, acc[j]);
        acc[j] = fmaf(xv.w, ev.w, acc[j]);
      }
    }
    {
      // Reference rounding: fl(e_sq - fl(2*dot)) then fl(t + x_sq). No FMA here.
#pragma clang fp contract(off)
#pragma unroll
      for (int j = 0; j < 8; ++j) {
        const float t    = esq[k + j] - 2.0f * acc[j];
        const float dist = t + myxsq;
        if (dist < best) { best = dist; bidx = k + j; }  // strict <: lowest k on ties
      }
    }
  }

  rv[w][lane] = best;
  ri[w][lane] = bidx;
  __syncthreads();
  if (tid < 64) {
    float bb = rv[0][tid];
    int   bi = ri[0][tid];
#pragma unroll
    for (int ww = 1; ww < 8; ++ww) {
      const float v = rv[ww][tid];
      if (v < bb) { bb = v; bi = ri[ww][tid]; }  // ascending k-order: lowest k on ties
    }
    idxout[n0 + tid] = bi;
    out[IDX_OFF + n0 + tid] = (float)bi;         // fp32 index output
  }
}

// K2: gather codebook rows per block into LDS, write x_q_st (fp32), accumulate loss.
__global__ __launch_bounds__(256, 2)
void vq_gather_kernel(const float* __restrict__ x, const float* __restrict__ cb,
                      const int* __restrict__ idxin, float* __restrict__ loss_acc,
                      float* __restrict__ out) {
  __shared__ float qs[64][260];
  __shared__ int   idx_s[64];
  __shared__ float wr[4];

  const int tid  = threadIdx.x;
  const int lane = tid & 63;
  const int w    = tid >> 6;
  const int n0   = blockIdx.x << 6;
  const int b    = n0 >> 10;
  const int hw0  = n0 & 1023;

  if (tid < 64) idx_s[tid] = idxin[n0 + tid];
  __syncthreads();

  const float4* __restrict__ cb4 = (const float4*)cb;
  for (int r = w; r < 64; r += 4) {
    const int c = idx_s[r];
    const float4 v = cb4[((size_t)c << 6) + lane];  // coalesced 1KB row read per wave
    *(float4*)&qs[r][lane << 2] = v;
  }
  __syncthreads();

  float lsum = 0.f;
  const size_t obase = (size_t)b * (DD * HWC) + hw0 + lane;
  for (int i = 0; i < 64; ++i) {
    const int d = (w << 6) + i;
    const size_t o = obase + (size_t)d * HWC;
    const float q  = qs[lane][d];
    const float xv = x[o];
    {
#pragma clang fp contract(off)
      const float df = q - xv;           // fl(x_q - x)
      out[o] = xv + df;                  // x_q_st = fl(x + fl(x_q - x)), fp32
      lsum = fmaf(df, df, lsum);         // loss accumulation (loose threshold)
    }
  }

  for (int off = 32; off > 0; off >>= 1) lsum += __shfl_down(lsum, off, 64);
  if (lane == 0) wr[w] = lsum;
  __syncthreads();
  if (tid == 0) atomicAdd(loss_acc, (wr[0] + wr[1]) + (wr[2] + wr[3]));
}

// K3: loss = 1.5 * mean((x_q - x)^2), fp32
__global__ void vq_loss_kernel(const float* __restrict__ loss_acc,
                               float* __restrict__ out) {
  if (threadIdx.x == 0) {
    const float m = loss_acc[0] / 8388608.0f;
    out[LOSS_OFF] = m + 0.5f * m;
  }
}

extern "C" void kernel_launch(void* const* d_in, const int* in_sizes, int n_in,
                              void* d_out, int out_size, void* d_ws, size_t ws_size,
                              hipStream_t stream) {
  const float* x  = (const float*)d_in[0];   // [32,256,32,32] fp32
  const float* cb = (const float*)d_in[1];   // [1024,256] fp32
  float* out = (float*)d_out;                // [x_q_st | loss | indices] fp32

  float* esq      = (float*)d_ws;            // 1024 floats
  float* loss_acc = esq + 1024;              // 1 float (zeroed by K0 each call)
  int*   idxbuf   = (int*)(esq + 1040);      // 32768 ints

  hipLaunchKernelGGL(vq_esq_kernel,    dim3(4),   dim3(256), 0, stream, cb, esq, loss_acc);
  hipLaunchKernelGGL(vq_argmin_kernel, dim3(512), dim3(512), 0, stream, x, cb, esq, idxbuf, out);
  hipLaunchKernelGGL(vq_gather_kernel, dim3(512), dim3(256), 0, stream, x, cb, idxbuf, loss_acc, out);
  hipLaunchKernelGGL(vq_loss_kernel,   dim3(1),   dim3(64),  0, stream, loss_acc, out);
}